// Round 6
// baseline (143.005 us; speedup 1.0000x reference)
//
#include <hip/hip_runtime.h>
#include <hip/hip_cooperative_groups.h>

namespace cg = cooperative_groups;

// NormEMAVectorQuantizer on MI355X (gfx950)
// N=8192 tokens, C=32, K=8192 codes, B=32, H*W=256.
// R23 = R22's cooperative mega-kernel, made launchable + guarded:
//  R22 post-mortem: ids all-zero/absmax 8192 (bf16(8191)) + z_q "passing" a
//  163.84 uniform threshold = output buffer untouched = cooperative launch
//  silently FAILED (1024 blocks needed 4 blocks/CU; MFMA AGPRs share the
//  unified VGPR file -> >128 regs; error never checked).
//  Changes: (a) 512 blocks, each owns TWO chunks (40KB LDS, a-frags reused
//  across both) -> co-residency needs only 2 blocks/CU (VGPR<=256, LDS<=80KB:
//  huge margin); (b) host-side occupancy query picks coop vs pipeline;
//  (c) cooperative launch return code checked; any failure falls back to the
//  proven R21 4-kernel pipeline (143us) in the same kernel_launch call.
// Fused phases (arithmetic byte-identical to proven R17 paths):
//  ph0 all blocks: stage 2 emb chunks fp32->bf16 into LDS (80B-padded rows).
//  ph1 blocks 0-36: token norm -> zn/znbf; zero packed; zero loss.  [grid.sync]
//  ph2: MFMA sweep both LDS chunks -> pmax[chunk][tok].             [grid.sync]
//  ph3: thr = gmax-eps (32 coalesced pmax loads); re-MFMA both resident
//       chunks; rare exact fp32 rescore + atomicMax into packed.    [grid.sync]
//  ph4: epilogue, 16 tokens + 16 codes per block (R17 k_final split finer).
// Certificate (R17, proven): bf16 dot err 2*err <= 0.0078 < eps=0.01 for unit
// rows -> every code that can be the fp32 argmax (incl. ties) is exact-
// rescored in fp32; key = (fmap(s)<<13)|(8191-code) = numpy lowest-index
// tie-break.
//
// Outputs (float32, concatenated):
//   [0 .. 262144)        z_q_out [B,C,H,W]
//   [262144]             loss (scalar)
//   [262145 .. 270337)   token_ids [B,H,W] as float
//   [270337 .. 532481)   new_embedding [K,C]
//   [532481 .. 540673)   new_cluster_sizes [K]

#define NTOK   8192
#define NCODE  8192
#define CDIM   32
#define HW     256
#define DECAYF 0.99f
#define EPSF   0.01f

#define OUT_ZQ   0
#define OUT_LOSS 262144
#define OUT_IDS  262145
#define OUT_EMB  270337
#define OUT_CS   532481

// workspace byte offsets (superset: fused + fallback pipeline)
#define WS_ZN     0u        // f32 [N,C]                = 1048576
#define WS_ZNBF   1048576u  // bf16 [N,C]               = 524288
#define WS_EBF    1572864u  // bf16 [K,C]  (fallback)   = 524288
#define WS_PMAX   2097152u  // f32 1MB: fused [32][N] / fallback pmaxT [N][32]
#define WS_PACK   3145728u  // u64 [N]                  = 65536
#define WS_EMBT   3211264u  // f32 [C][K]  (fallback)   = 1048576 (end 4259840)

#define CHUNK  256
#define NCHUNK (NCODE / CHUNK)  // 32
#define TILES  (CHUNK / 16)     // 16

typedef __attribute__((ext_vector_type(8))) short bf16x8;
typedef __attribute__((ext_vector_type(4))) float f32x4;

__device__ inline unsigned short f2bf(float x) {
    unsigned u = __float_as_uint(x);
    return (unsigned short)((u + 0x7FFFu + ((u >> 16) & 1u)) >> 16);
}
__device__ inline unsigned fmap(float s) {   // monotonic f32 -> u32
    unsigned u = __float_as_uint(s);
    return (u & 0x80000000u) ? ~u : (u | 0x80000000u);
}

// ===================== fused cooperative kernel (512 blocks) ==================
__global__ __launch_bounds__(256) void k_fused(
    const float* __restrict__ z, const float* __restrict__ emb,
    const float* __restrict__ cs, float* __restrict__ zn,
    unsigned short* __restrict__ znbf, float* __restrict__ pmax,
    unsigned long long* __restrict__ packed, float* __restrict__ out) {
    __shared__ float4 lbs5[2 * CHUNK * 5];        // 40 KiB, 80B rows, 2 chunks
    __shared__ float lmax[256];
    __shared__ float lesum[16][32];
    __shared__ int lbins[16];
    __shared__ int lsid[16];
    __shared__ float ls4[4];

    cg::grid_group grid = cg::this_grid();
    const int t = threadIdx.x, bid = blockIdx.x;
    const int bx = bid & 31;                      // token group (256 tokens)
    const int cpair = bid >> 5;                   // 0..15: chunk pair
    const int kb0 = cpair * (2 * CHUNK);

    // ---- phase 0: stage 2 emb chunks fp32->bf16 into LDS -------------------
#pragma unroll
    for (int cc = 0; cc < 2; ++cc) {
        const float* src = emb + (size_t)(kb0 + cc * CHUNK) * CDIM;
        float4* dst = lbs5 + cc * CHUNK * 5;
#pragma unroll
        for (int j = 0; j < 4; ++j) {
            int u = t + j * 256, row = u >> 2, seg = u & 3;
            const float4* p = (const float4*)(src + row * CDIM + seg * 8);
            float4 x4 = p[0], y4 = p[1];
            union { float4 f4; unsigned short us[8]; } w;
            w.us[0] = f2bf(x4.x); w.us[1] = f2bf(x4.y);
            w.us[2] = f2bf(x4.z); w.us[3] = f2bf(x4.w);
            w.us[4] = f2bf(y4.x); w.us[5] = f2bf(y4.y);
            w.us[6] = f2bf(y4.z); w.us[7] = f2bf(y4.w);
            dst[row * 5 + seg] = w.f4;
        }
    }

    // ---- phase 1 (37 blocks, overlaps staging): norm + zero packed/loss ----
    if (bid < 32) {                               // token norm -> zn, znbf
        int n = bid * 256 + t;
        int b = n >> 8, hw = n & 255;
        const float* zp = z + (size_t)b * (CDIM * HW) + hw;
        float v[CDIM];
        float ss = 0.f;
#pragma unroll
        for (int c = 0; c < CDIM; ++c) {
            float tv = zp[c * HW];                // coalesced per c
            v[c] = tv;
            ss += tv * tv;
        }
        float dn = fmaxf(sqrtf(ss), 1e-12f);
        float* o = zn + (size_t)n * CDIM;
        unsigned short* ob = znbf + (size_t)n * CDIM;
#pragma unroll
        for (int c = 0; c < CDIM; ++c) {
            float tv = v[c] / dn;
            o[c] = tv;
            ob[c] = f2bf(tv);
        }
    } else if (bid < 36) {                        // zero packed
        int base = (bid - 32) * 2048 + t;
#pragma unroll
        for (int j = 0; j < 8; ++j) packed[base + j * 256] = 0ull;
    } else if (bid == 36) {
        if (t == 0) out[OUT_LOSS] = 0.f;
    }

    __syncthreads();
    grid.sync();                                  // zn/znbf/packed/loss ready

    // ---- phase 2: MFMA sweep both chunks -> pmax[chunk][tok] ---------------
    const int wave = t >> 6, lane = t & 63;
    const int col = lane & 15, quad = lane >> 4;
    const int wtok = bx * 256 + wave * 64;

    bf16x8 a[4];                                  // token frags, reused for
#pragma unroll                                    // both chunks + phase 3
    for (int f = 0; f < 4; ++f)
        a[f] = *(const bf16x8*)(znbf + (size_t)(wtok + f * 16 + col) * CDIM + quad * 8);

    const f32x4 zero4 = {0.f, 0.f, 0.f, 0.f};
#pragma unroll 1
    for (int cc = 0; cc < 2; ++cc) {
        const bf16x8* bl = (const bf16x8*)(lbs5 + cc * CHUNK * 5);
        float m[4][4];
#pragma unroll
        for (int f = 0; f < 4; ++f)
#pragma unroll
            for (int r = 0; r < 4; ++r) m[f][r] = -1e30f;
        for (int tt = 0; tt < TILES; ++tt) {
            bf16x8 b = bl[(tt * 16 + col) * 5 + quad];
#pragma unroll
            for (int f = 0; f < 4; ++f) {
                f32x4 d = __builtin_amdgcn_mfma_f32_16x16x32_bf16(a[f], b, zero4, 0, 0, 0);
#pragma unroll
                for (int r = 0; r < 4; ++r) m[f][r] = fmaxf(m[f][r], d[r]);
            }
        }
#pragma unroll
        for (int f = 0; f < 4; ++f)
#pragma unroll
            for (int r = 0; r < 4; ++r) {
                float v = m[f][r];
#pragma unroll
                for (int s = 1; s < 16; s <<= 1) v = fmaxf(v, __shfl_xor(v, s));
                if (col == 0) lmax[wave * 64 + f * 16 + quad * 4 + r] = v;
            }
        __syncthreads();
        pmax[(size_t)(cpair * 2 + cc) * NTOK + bx * 256 + t] = lmax[t];
        __syncthreads();                          // lmax reused next cc
    }
    grid.sync();                                  // all chunk maxima ready

    // ---- phase 3: global thr + re-sweep (LDS chunks + a-frags still live) --
    {
        int tok = bx * 256 + t;
        float mx = -1e30f;
#pragma unroll
        for (int ch = 0; ch < NCHUNK; ++ch)
            mx = fmaxf(mx, pmax[(size_t)ch * NTOK + tok]);
        lmax[t] = mx - EPSF;
    }
    __syncthreads();

    float thr[4][4];
#pragma unroll
    for (int f = 0; f < 4; ++f)
#pragma unroll
        for (int r = 0; r < 4; ++r)
            thr[f][r] = lmax[wave * 64 + f * 16 + quad * 4 + r];

#pragma unroll 1
    for (int cc = 0; cc < 2; ++cc) {
        const bf16x8* bl = (const bf16x8*)(lbs5 + cc * CHUNK * 5);
        const int kbase = kb0 + cc * CHUNK;
        for (int tt = 0; tt < TILES; ++tt) {
            bf16x8 b = bl[(tt * 16 + col) * 5 + quad];
#pragma unroll
            for (int f = 0; f < 4; ++f) {
                f32x4 d = __builtin_amdgcn_mfma_f32_16x16x32_bf16(a[f], b, zero4, 0, 0, 0);
#pragma unroll
                for (int r = 0; r < 4; ++r) {
                    if (d[r] >= thr[f][r]) {      // rare: ~1.05/token total
                        int tok = wtok + f * 16 + quad * 4 + r;
                        int code = kbase + tt * 16 + col;
                        const float* zp = zn + (size_t)tok * CDIM;
                        const float* ep = emb + (size_t)code * CDIM;
                        float a0 = 0.f, a1 = 0.f, a2 = 0.f, a3 = 0.f;
#pragma unroll
                        for (int j = 0; j < 8; ++j) {
                            a0 = __builtin_fmaf(zp[4 * j + 0], ep[4 * j + 0], a0);
                            a1 = __builtin_fmaf(zp[4 * j + 1], ep[4 * j + 1], a1);
                            a2 = __builtin_fmaf(zp[4 * j + 2], ep[4 * j + 2], a2);
                            a3 = __builtin_fmaf(zp[4 * j + 3], ep[4 * j + 3], a3);
                        }
                        float sc = (a0 + a1) + (a2 + a3);
                        atomicMax(packed + tok,
                                  ((unsigned long long)fmap(sc) << 13) |
                                  (unsigned long long)(8191 - code));
                    }
                }
            }
        }
    }
    grid.sync();                                  // all argmax keys final

    // ---- phase 4: epilogue, 16 tokens + 16 codes per block -----------------
    if (t < 16) lbins[t] = 0;
#pragma unroll
    for (int i = 0; i < 2; ++i) {
        int idx = i * 256 + t;
        lesum[idx >> 5][idx & 31] = 0.f;
    }
    const int tok0 = bid * 16, kb2 = bid * 16;
    if (t < 16) {                                 // unpack ids for our tokens
        int n = tok0 + t;
        int id = 8191 - (int)(packed[n] & 8191ull);
        lsid[t] = id;
        out[OUT_IDS + n] = (float)id;
    }
    __syncthreads();

    // z_q gather + transpose-out + loss partial (2 elems/thread)
    float s = 0.f;
#pragma unroll
    for (int i = 0; i < 2; ++i) {
        int idx = i * 256 + t;
        int tl = idx >> 5, c = idx & 31;
        int n = tok0 + tl;
        int id = lsid[tl];
        float ev = emb[(size_t)id * CDIM + c];
        float zv = zn[(size_t)n * CDIM + c];
        int b = n >> 8, hw = n & 255;
        out[OUT_ZQ + ((size_t)b * CDIM + c) * HW + hw] = ev;
        float dd = ev - zv;
        s += dd * dd;
    }
#pragma unroll
    for (int off = 32; off > 0; off >>= 1) s += __shfl_down(s, off);
    if (lane == 0) ls4[wave] = s;

    // bins + esum: scan all tokens for hits in our 16-code window
    for (int i = 0; i < 32; ++i) {
        int n = i * 256 + t;                      // coalesced
        int id = 8191 - (int)(packed[n] & 8191ull);
        unsigned kl = (unsigned)(id - kb2);
        if (kl < 16u) {
            atomicAdd(&lbins[kl], 1);
            const float* zp = zn + (size_t)n * CDIM;
#pragma unroll
            for (int c = 0; c < CDIM; ++c)
                atomicAdd(&lesum[kl][c], zp[c]);
        }
    }
    __syncthreads();
    if (t == 0)
        atomicAdd(out + OUT_LOSS,
                  (ls4[0] + ls4[1] + ls4[2] + ls4[3]) * (1.0f / 262144.0f));

    // EMA update + renormalize for our 16 codes (2 elems/thread)
#pragma unroll
    for (int i = 0; i < 2; ++i) {
        int idx = i * 256 + t;
        int kl = idx >> 5, c = idx & 31;
        int k = kb2 + kl;
        int bi = lbins[kl];
        float bf = (float)bi;
        bool zero = (bi == 0);
        float tv = lesum[kl][c] / (zero ? 1.0f : bf);
        float ss = tv * tv;
#pragma unroll
        for (int sh = 1; sh < 32; sh <<= 1) ss += __shfl_xor(ss, sh);
        float dn = fmaxf(sqrtf(ss), 1e-12f);
        float ew = emb[(size_t)k * CDIM + c];
        float en = zero ? ew : (tv / dn);
        float w = ew * DECAYF + (1.0f - DECAYF) * en;
        float ss2 = w * w;
#pragma unroll
        for (int sh = 1; sh < 32; sh <<= 1) ss2 += __shfl_xor(ss2, sh);
        float d2 = fmaxf(sqrtf(ss2), 1e-12f);
        out[OUT_EMB + (size_t)k * CDIM + c] = w / d2;
        if (c == 0) out[OUT_CS + k] = cs[k] * DECAYF + (1.0f - DECAYF) * bf;
    }
}

// ===================== fallback: R21 4-kernel pipeline (proven) ==============
__device__ inline void stage_chunk(const unsigned short* __restrict__ ebf,
                                   int kbase, float4* lbs5, int t) {
    const float4* src = (const float4*)(ebf + (size_t)kbase * CDIM);
#pragma unroll
    for (int j = 0; j < 4; ++j) {
        int u = t + j * 256;
        int row = u >> 2, seg = u & 3;
        lbs5[row * 5 + seg] = src[u];
    }
}

__global__ __launch_bounds__(256) void p_prep(const float* __restrict__ z,
                                              const float* __restrict__ emb,
                                              float* __restrict__ zn,
                                              unsigned short* __restrict__ znbf,
                                              unsigned short* __restrict__ ebf,
                                              float* __restrict__ embT,
                                              float* __restrict__ out) {
    __shared__ float tile[32][65];
    int bid = blockIdx.x, t = threadIdx.x;
    if (bid < 32) {
        int n = bid * 256 + t;
        int b = n >> 8, hw = n & 255;
        const float* zp = z + (size_t)b * (CDIM * HW) + hw;
        float v[CDIM];
        float ss = 0.f;
#pragma unroll
        for (int c = 0; c < CDIM; ++c) {
            float tv = zp[c * HW];
            v[c] = tv;
            ss += tv * tv;
        }
        float d = fmaxf(sqrtf(ss), 1e-12f);
        float* o = zn + (size_t)n * CDIM;
        unsigned short* ob = znbf + (size_t)n * CDIM;
#pragma unroll
        for (int c = 0; c < CDIM; ++c) {
            float tv = v[c] / d;
            o[c] = tv;
            ob[c] = f2bf(tv);
        }
    } else if (bid < 160) {
        int blk = bid - 32;
        int r0 = blk * 64;
        int base = blk * 2048 + t * 8;
        const float4* s = (const float4*)(emb + base);
        float4 x4 = s[0], y4 = s[1];
        ushort4 u0 = {f2bf(x4.x), f2bf(x4.y), f2bf(x4.z), f2bf(x4.w)};
        ushort4 u1 = {f2bf(y4.x), f2bf(y4.y), f2bf(y4.z), f2bf(y4.w)};
        *(ushort4*)(ebf + base) = u0;
        *(ushort4*)(ebf + base + 4) = u1;
        int lr = t >> 2, c0 = (t & 3) * 8;
        tile[c0 + 0][lr] = x4.x; tile[c0 + 1][lr] = x4.y;
        tile[c0 + 2][lr] = x4.z; tile[c0 + 3][lr] = x4.w;
        tile[c0 + 4][lr] = y4.x; tile[c0 + 5][lr] = y4.y;
        tile[c0 + 6][lr] = y4.z; tile[c0 + 7][lr] = y4.w;
        __syncthreads();
        int c = t >> 3, seg = t & 7;
        float4 w0 = {tile[c][seg * 8 + 0], tile[c][seg * 8 + 1],
                     tile[c][seg * 8 + 2], tile[c][seg * 8 + 3]};
        float4 w1 = {tile[c][seg * 8 + 4], tile[c][seg * 8 + 5],
                     tile[c][seg * 8 + 6], tile[c][seg * 8 + 7]};
        float* dst = embT + (size_t)c * NCODE + r0 + seg * 8;
        *(float4*)dst = w0;
        *(float4*)(dst + 4) = w1;
    } else {
        if (t == 0) out[OUT_LOSS] = 0.f;
    }
}

__global__ __launch_bounds__(256) void p_max(const unsigned short* __restrict__ znbf,
                                             const unsigned short* __restrict__ ebf,
                                             float* __restrict__ pmaxT) {
    __shared__ float4 lbs5[CHUNK * 5];
    __shared__ float lmax[256];
    int kbase = blockIdx.y * CHUNK;
    stage_chunk(ebf, kbase, lbs5, threadIdx.x);
    __syncthreads();

    int wave = threadIdx.x >> 6, lane = threadIdx.x & 63;
    int col = lane & 15, quad = lane >> 4;
    int wtok = blockIdx.x * 256 + wave * 64;

    bf16x8 a[4];
#pragma unroll
    for (int f = 0; f < 4; ++f)
        a[f] = *(const bf16x8*)(znbf + (size_t)(wtok + f * 16 + col) * CDIM + quad * 8);

    const bf16x8* bl = (const bf16x8*)lbs5;
    const f32x4 zero4 = {0.f, 0.f, 0.f, 0.f};
    float m[4][4];
#pragma unroll
    for (int f = 0; f < 4; ++f)
#pragma unroll
        for (int r = 0; r < 4; ++r) m[f][r] = -1e30f;

    for (int t = 0; t < TILES; ++t) {
        bf16x8 b = bl[(t * 16 + col) * 5 + quad];
#pragma unroll
        for (int f = 0; f < 4; ++f) {
            f32x4 d = __builtin_amdgcn_mfma_f32_16x16x32_bf16(a[f], b, zero4, 0, 0, 0);
#pragma unroll
            for (int r = 0; r < 4; ++r) m[f][r] = fmaxf(m[f][r], d[r]);
        }
    }
#pragma unroll
    for (int f = 0; f < 4; ++f)
#pragma unroll
        for (int r = 0; r < 4; ++r) {
            float v = m[f][r];
#pragma unroll
            for (int s = 1; s < 16; s <<= 1) v = fmaxf(v, __shfl_xor(v, s));
            if (col == 0) lmax[wave * 64 + f * 16 + quad * 4 + r] = v;
        }
    __syncthreads();
    pmaxT[(size_t)(blockIdx.x * 256 + threadIdx.x) * NCHUNK + blockIdx.y] =
        lmax[threadIdx.x];
}

__global__ __launch_bounds__(256) void p_rescan(const float* __restrict__ zn,
                                                const float* __restrict__ embT,
                                                const float* __restrict__ pmaxT,
                                                unsigned long long* __restrict__ packed) {
    int wave = threadIdx.x >> 6, lane = threadIdx.x & 63;
    int n = blockIdx.x * 4 + wave;

    float pm = -1e30f;
    if (lane < 32) pm = pmaxT[(size_t)n * NCHUNK + lane];
    float mx = pm;
#pragma unroll
    for (int s = 1; s < 64; s <<= 1) mx = fmaxf(mx, __shfl_xor(mx, s));
    float thr = mx - EPSF;
    unsigned m32 = (unsigned)(__ballot(pm >= thr) & 0xFFFFFFFFull);

    float zr[CDIM];
    const float4* zp4 = (const float4*)(zn + (size_t)n * CDIM);
#pragma unroll
    for (int j = 0; j < 8; ++j) {
        float4 v4 = zp4[j];
        zr[4 * j + 0] = v4.x;
        zr[4 * j + 1] = v4.y;
        zr[4 * j + 2] = v4.z;
        zr[4 * j + 3] = v4.w;
    }

    unsigned long long kbest = 0ull;
    while (m32) {
        int ch = __ffs(m32) - 1;
        m32 &= m32 - 1;
        const float* bp = embT + ch * CHUNK + 4 * lane;
        float acc[4][4] = {};
#pragma unroll
        for (int c = 0; c < CDIM; ++c) {
            float4 e4 = *(const float4*)(bp + (size_t)c * NCODE);
            int r = c & 3;
            acc[r][0] = __builtin_fmaf(zr[c], e4.x, acc[r][0]);
            acc[r][1] = __builtin_fmaf(zr[c], e4.y, acc[r][1]);
            acc[r][2] = __builtin_fmaf(zr[c], e4.z, acc[r][2]);
            acc[r][3] = __builtin_fmaf(zr[c], e4.w, acc[r][3]);
        }
#pragma unroll
        for (int j = 0; j < 4; ++j) {
            float s = (acc[0][j] + acc[1][j]) + (acc[2][j] + acc[3][j]);
            int code = ch * CHUNK + 4 * lane + j;
            unsigned long long key = ((unsigned long long)fmap(s) << 13) |
                                     (unsigned long long)(8191 - code);
            kbest = kbest > key ? kbest : key;
        }
    }
#pragma unroll
    for (int s = 1; s < 64; s <<= 1) {
        unsigned long long o = __shfl_xor(kbest, s);
        kbest = kbest > o ? kbest : o;
    }
    if (lane == 0) packed[n] = kbest;
}

__global__ __launch_bounds__(256) void p_final(const unsigned long long* __restrict__ packed,
                                               const float* __restrict__ zn,
                                               const float* __restrict__ emb,
                                               const float* __restrict__ cs,
                                               float* __restrict__ out) {
    __shared__ float lesum[32][32];
    __shared__ int lbins[32];
    __shared__ int lsid[32];
    __shared__ float ls4[4];

    int blk = blockIdx.x, t = threadIdx.x;
    int wave = t >> 6, lane = t & 63;
    int tok0 = blk * 32, kbase = blk * 32;

    if (t < 32) lbins[t] = 0;
#pragma unroll
    for (int i = 0; i < 4; ++i) {
        int idx = i * 256 + t;
        lesum[idx >> 5][idx & 31] = 0.f;
    }
    if (t < 32) {
        int n = tok0 + t;
        int id = 8191 - (int)(packed[n] & 8191ull);
        lsid[t] = id;
        out[OUT_IDS + n] = (float)id;
    }
    __syncthreads();

    float s = 0.f;
#pragma unroll
    for (int i = 0; i < 4; ++i) {
        int idx = i * 256 + t;
        int tl = idx >> 5, c = idx & 31;
        int n = tok0 + tl;
        int id = lsid[tl];
        float ev = emb[(size_t)id * CDIM + c];
        float zv = zn[(size_t)n * CDIM + c];
        int b = n >> 8, hw = n & 255;
        out[OUT_ZQ + ((size_t)b * CDIM + c) * HW + hw] = ev;
        float dd = ev - zv;
        s += dd * dd;
    }
#pragma unroll
    for (int off = 32; off > 0; off >>= 1) s += __shfl_down(s, off);
    if (lane == 0) ls4[wave] = s;
    __syncthreads();
    if (t == 0)
        atomicAdd(out + OUT_LOSS,
                  (ls4[0] + ls4[1] + ls4[2] + ls4[3]) * (1.0f / 262144.0f));

    for (int i = 0; i < 32; ++i) {
        int n = i * 256 + t;
        int id = 8191 - (int)(packed[n] & 8191ull);
        unsigned kl = (unsigned)(id - kbase);
        if (kl < 32u) {
            atomicAdd(&lbins[kl], 1);
            const float* zp = zn + (size_t)n * CDIM;
#pragma unroll
            for (int c = 0; c < CDIM; ++c)
                atomicAdd(&lesum[kl][c], zp[c]);
        }
    }
    __syncthreads();

#pragma unroll
    for (int i = 0; i < 4; ++i) {
        int idx = i * 256 + t;
        int kl = idx >> 5, c = idx & 31;
        int k = kbase + kl;
        int bi = lbins[kl];
        float bf = (float)bi;
        bool zero = (bi == 0);
        float tv = lesum[kl][c] / (zero ? 1.0f : bf);
        float ss = tv * tv;
#pragma unroll
        for (int sh = 1; sh < 32; sh <<= 1) ss += __shfl_xor(ss, sh);
        float d = fmaxf(sqrtf(ss), 1e-12f);
        float ew = emb[(size_t)k * CDIM + c];
        float en = zero ? ew : (tv / d);
        float w = ew * DECAYF + (1.0f - DECAYF) * en;
        float ss2 = w * w;
#pragma unroll
        for (int sh = 1; sh < 32; sh <<= 1) ss2 += __shfl_xor(ss2, sh);
        float d2 = fmaxf(sqrtf(ss2), 1e-12f);
        out[OUT_EMB + (size_t)k * CDIM + c] = w / d2;
        if (c == 0) out[OUT_CS + k] = cs[k] * DECAYF + (1.0f - DECAYF) * bf;
    }
}

extern "C" void kernel_launch(void* const* d_in, const int* in_sizes, int n_in,
                              void* d_out, int out_size, void* d_ws, size_t ws_size,
                              hipStream_t stream) {
    const float* z   = (const float*)d_in[0];   // [32,32,16,16]
    const float* emb = (const float*)d_in[1];   // [8192,32]
    const float* cs  = (const float*)d_in[2];   // [8192]
    float* out = (float*)d_out;
    char* ws = (char*)d_ws;

    float* zn                  = (float*)(ws + WS_ZN);
    unsigned short* znbf       = (unsigned short*)(ws + WS_ZNBF);
    unsigned short* ebf        = (unsigned short*)(ws + WS_EBF);
    float* pmax                = (float*)(ws + WS_PMAX);
    unsigned long long* packed = (unsigned long long*)(ws + WS_PACK);
    float* embT                = (float*)(ws + WS_EMBT);

    // one-time capture-safe occupancy check: 512-block coop needs >=2 blk/CU
    static int coop = -1;
    if (coop < 0) {
        int nb = 0;
        hipError_t e = hipOccupancyMaxActiveBlocksPerMultiprocessor(&nb, k_fused, 256, 0);
        coop = (e == hipSuccess && nb >= 2) ? 1 : 0;
        if (e != hipSuccess) (void)hipGetLastError();
    }

    if (coop) {
        void* args[] = {(void*)&z, (void*)&emb, (void*)&cs, (void*)&zn,
                        (void*)&znbf, (void*)&pmax, (void*)&packed, (void*)&out};
        hipError_t e = hipLaunchCooperativeKernel(k_fused, dim3(512), dim3(256),
                                                  args, 0, stream);
        if (e == hipSuccess) return;
        (void)hipGetLastError();                  // clear; fall through
        coop = 0;
    }

    // fallback: proven R21 pipeline
    p_prep<<<dim3(161), 256, 0, stream>>>(z, emb, zn, znbf, ebf, embT, out);
    p_max<<<dim3(NTOK / 256, NCHUNK), 256, 0, stream>>>(znbf, ebf, pmax);
    p_rescan<<<dim3(NTOK / 4), 256, 0, stream>>>(zn, embT, pmax, packed);
    p_final<<<dim3(256), 256, 0, stream>>>(packed, zn, emb, cs, out);
}